// Round 19
// baseline (174.854 us; speedup 1.0000x reference)
//
#include <hip/hip_runtime.h>
#include <stdint.h>

#define CIN 256
#define COUT 256
#define RANK 64
#define H_ 112
#define W_ 112
#define HW_ (112*112)

typedef short bf16x8 __attribute__((ext_vector_type(8)));   // 8 bf16 = 4 VGPRs
typedef float f32x4 __attribute__((ext_vector_type(4)));

__device__ __forceinline__ unsigned short rne1(float a){
  unsigned ua = __builtin_bit_cast(unsigned, a);
  ua += 0x7FFFu + ((ua >> 16) & 1u);
  return (unsigned short)(ua >> 16);
}
// packed fp32x2 -> bf16x2 (lo = a, hi = b), single VALU op
__device__ __forceinline__ unsigned cvtpk(float a, float b){
  unsigned r;
  asm("v_cvt_pk_bf16_f32 %0, %1, %2" : "=v"(r) : "v"(a), "v"(b));
  return r;
}

// ---- K0a: w_sum[o][i] = sum_k w_head[k][o][i] ----
__global__ __launch_bounds__(256) void k_wsum(const float* __restrict__ wh,
                                              float* __restrict__ wsum){
  int o = blockIdx.x, i = threadIdx.x;
  float s = 0.f;
  for (int k = 0; k < RANK; ++k) s += wh[(k*COUT + o)*CIN + i];
  wsum[o*CIN + i] = s;
}

// ---- K0b: blocks [0,192): w_eff[dh][r][i] (bf16); blocks [192,448): wtp[o][dw][r] (bf16)
__global__ __launch_bounds__(256) void k_pre2(const float* __restrict__ wb,
                                              const float* __restrict__ wsum,
                                              unsigned short* __restrict__ weff,
                                              const float* __restrict__ wt,
                                              unsigned short* __restrict__ wtp){
  const int tid = threadIdx.x;
  if (blockIdx.x < 192){
    int bid = blockIdx.x;            // dh*64 + r
    int dh = bid >> 6, r = bid & 63;
    float s = 0.f;
    for (int o = 0; o < COUT; ++o)
      s += wb[(r*COUT + o)*3 + dh] * wsum[o*CIN + tid];
    weff[bid*CIN + tid] = rne1(s);
  } else {
    int o = blockIdx.x - 192;
    if (tid < 192){
      int dw = tid >> 6, r = tid & 63;
      wtp[o*192 + tid] = rne1(wt[(o*RANK + r)*3 + dw]);
    }
  }
}

// ---- K_all: x fp32 -> in-kernel bf16 transpose-stage -> body GEMM -> LDS y2
//             -> tail GEMM -> out. Depth-2 counted-vmcnt pipeline, split barriers.
// CONSOLIDATED BEST (R14 config): slab stride 72, h1 base 8208 (LDS 32832).
// Session A/B record: H1OFF=8176/LDS=32768 (R18) raised LDS-capacity to 4
// blocks/CU but occupancy did NOT rise (register-bound ~192 unified regs/wave)
// and dur regressed 146.7->159.8 us -> keep 8208.
// Stage layout per step: [4 rows][4 g][112 slots][8 c] bf16, slot = w^(g&3)^((w>>2)&3).
__global__ __launch_bounds__(256,2) void k_all(const float* __restrict__ x,
                                               const unsigned short* __restrict__ weff,
                                               const unsigned short* __restrict__ wtp,
                                               const float* __restrict__ bias,
                                               float* __restrict__ out,
                                               unsigned cpx){
  __shared__ alignas(16) unsigned short lds[16416];  // 32832 B: stage (28672) / y2 slab
  const int tid  = threadIdx.x;
  const int wid  = tid >> 6, lane = tid & 63, g = lane >> 4, l15 = lane & 15;
  const unsigned orig = blockIdx.x;
  const unsigned wg   = (orig & 7u)*cpx + (orig >> 3);   // bijective XCD swizzle
  const int bb   = wg / 56, hb = wg % 56;
  const int h0   = hb*2;
  const int hloc = wid >> 1, rhalf = wid & 1;

  // staging lane roles: q_st = w-quad, cpair = channel pair 0..15
  const int q_st = lane & 3, cpair = lane >> 2;
  const int g_st = cpair >> 2, cp3 = cpair & 3;
  const int grow = h0 - 1 + wid;
  const bool rok = (grow >= 0) && (grow < H_);
  const float* xrow = x + ((size_t)bb*CIN + cpair*2)*HW_ + (size_t)(rok ? grow : 0)*W_;
  unsigned char* const stg = (unsigned char*)lds;
  const int cxor = (g_st ^ q_st) & 3;                  // write slot XOR
  const int lxor = (l15 ^ (g & 3) ^ ((l15 >> 2) & 3)); // read slot low bits

  // ---- phase A: 8 steps x 32 ch; depth-2 reg pipeline ----
  f32x4 acc[2][7];
  #pragma unroll
  for (int a = 0; a < 2; ++a)
    #pragma unroll
    for (int b = 0; b < 7; ++b) acc[a][b] = (f32x4){0.f,0.f,0.f,0.f};

  f32x4  xa[2][7], xb[2][7];      // x fp32 in-flight, 2 sets
  bf16x8 afp[2][3][2];            // weff A-frags, 2 sets

  auto ISSUE_A = [&](int t){
    const int s = t & 1;
    #pragma unroll
    for (int dh = 0; dh < 3; ++dh){
      const unsigned short* ab = weff + (size_t)(dh*64 + rhalf*32 + l15)*CIN + t*32 + g*8;
      afp[s][dh][0] = *(const bf16x8*)(ab);
      afp[s][dh][1] = *(const bf16x8*)(ab + 16*CIN);
    }
  };
  auto ISSUE_X = [&](int t){
    const int s = t & 1;
    const float* pa = xrow + (size_t)t*32*HW_;
    #pragma unroll
    for (int j = 0; j < 7; ++j){
      const int w0 = 16*j + q_st*4;
      if (rok){
        xa[s][j] = *(const f32x4*)(pa + w0);
        xb[s][j] = *(const f32x4*)(pa + HW_ + w0);
      } else {
        xa[s][j] = (f32x4){0.f,0.f,0.f,0.f};
        xb[s][j] = (f32x4){0.f,0.f,0.f,0.f};
      }
    }
  };
  auto WRITE = [&](int t){
    const int s = t & 1;
    unsigned char* base = stg + wid*7168 + g_st*1792 + cp3*4;
    #pragma unroll
    for (int j = 0; j < 7; ++j){
      const int w0 = 16*j + q_st*4;
      #pragma unroll
      for (int k = 0; k < 4; ++k){
        unsigned pk = cvtpk(xa[s][j][k], xb[s][j][k]);
        *(unsigned*)(base + (unsigned)(w0*16) + (unsigned)((k ^ cxor) << 4)) = pk;
      }
    }
  };
  auto MSTEP = [&](int t){
    const int s = t & 1;
    #pragma unroll
    for (int dh = 0; dh < 3; ++dh){
      const unsigned char* rowb = stg + (hloc + dh)*7168 + g*1792 + lxor*16;
      #pragma unroll
      for (int wt = 0; wt < 7; ++wt){
        bf16x8 bfv = *(const bf16x8*)(rowb + wt*256);
        acc[0][wt] = __builtin_amdgcn_mfma_f32_16x16x32_bf16(afp[s][dh][0], bfv, acc[0][wt], 0, 0, 0);
        acc[1][wt] = __builtin_amdgcn_mfma_f32_16x16x32_bf16(afp[s][dh][1], bfv, acc[1][wt], 0, 0, 0);
      }
    }
  };

  ISSUE_A(0); ISSUE_X(0); ISSUE_A(1); ISSUE_X(1);
  #pragma unroll
  for (int t = 0; t < 8; ++t){
    // retire pair t (A+x, 20 ops), leave pair t+1 (20) in flight
    if (t < 7) asm volatile("s_waitcnt vmcnt(20)" ::: "memory");
    else       asm volatile("s_waitcnt vmcnt(0)"  ::: "memory");
    WRITE(t);
    asm volatile("s_waitcnt lgkmcnt(0)" ::: "memory");   // ds_writes visible...
    __builtin_amdgcn_s_barrier();                        // ...to all waves; vm survives
    if (t < 6) ISSUE_X(t + 2);       // x early: ~2-step prefetch distance
    MSTEP(t);                        // consumes afp[t&1]
    if (t < 6) ISSUE_A(t + 2);       // A-frags late (reuse afp[t&1] after use)
    __builtin_amdgcn_s_barrier();    // reads done before next WRITE
  }

  // ---- phase B: acc -> LDS y2 slab [2 h][114 w'][72 stride] (bf16), w' = w+1 ----
  unsigned short* y2b = lds;
  if (tid < 32){
    int hh = tid >> 4, wsel = (tid >> 3) & 1, rq = tid & 7;
    *(uint4*)(y2b + hh*8208 + (wsel ? 113 : 0)*72 + rq*8) = (uint4){0,0,0,0};
  }
  #pragma unroll
  for (int wt = 0; wt < 7; ++wt){
    #pragma unroll
    for (int rt = 0; rt < 2; ++rt){
      uint2 st;
      st.x = cvtpk(acc[rt][wt][0], acc[rt][wt][1]);
      st.y = cvtpk(acc[rt][wt][2], acc[rt][wt][3]);
      *(uint2*)(y2b + hloc*8208 + (wt*16 + l15 + 1)*72 + rhalf*32 + rt*16 + g*4) = st;
    }
  }
  __syncthreads();

  // ---- phase C: tail GEMM, 4 passes of 32 o per wave ----
  const int h = h0 + hloc;
  #pragma unroll
  for (int opass = 0; opass < 4; ++opass){
    const int obase = rhalf*128 + opass*32;
    f32x4 a2[2][7];
    #pragma unroll
    for (int a = 0; a < 2; ++a)
      #pragma unroll
      for (int b = 0; b < 7; ++b) a2[a][b] = (f32x4){0.f,0.f,0.f,0.f};

    #pragma unroll
    for (int s = 0; s < 6; ++s){       // k-step: dw = s>>1, r-half = s&1
      bf16x8 afc[2];
      const unsigned short* ab = wtp + (size_t)(obase + l15)*192 + s*32 + g*8;
      #pragma unroll
      for (int rt = 0; rt < 2; ++rt)
        afc[rt] = *(const bf16x8*)(ab + rt*16*192);
      const unsigned short* qb = y2b + hloc*8208 + (l15 + (s >> 1))*72 + (s & 1)*32 + g*8;
      #pragma unroll
      for (int wt = 0; wt < 7; ++wt){
        bf16x8 bvv = *(const bf16x8*)(qb + wt*16*72);
        #pragma unroll
        for (int rt = 0; rt < 2; ++rt)
          a2[rt][wt] = __builtin_amdgcn_mfma_f32_16x16x32_bf16(afc[rt], bvv, a2[rt][wt], 0, 0, 0);
      }
    }

    float* ob = out + ((size_t)(bb*COUT) + obase)*HW_ + h*W_;
    #pragma unroll
    for (int rt = 0; rt < 2; ++rt){
      #pragma unroll
      for (int ii = 0; ii < 4; ++ii){
        float bvv = bias[obase + rt*16 + g*4 + ii];
        #pragma unroll
        for (int wt = 0; wt < 7; ++wt)
          ob[(size_t)(rt*16 + g*4 + ii)*HW_ + wt*16 + l15] = a2[rt][wt][ii] + bvv;
      }
    }
  }
}

extern "C" void kernel_launch(void* const* d_in, const int* in_sizes, int n_in,
                              void* d_out, int out_size, void* d_ws, size_t ws_size,
                              hipStream_t stream) {
  const float* x      = (const float*)d_in[0];
  const float* w_head = (const float*)d_in[1];
  const float* w_body = (const float*)d_in[2];
  const float* w_tail = (const float*)d_in[3];
  const float* b_tail = (const float*)d_in[4];
  float* out = (float*)d_out;
  char* ws = (char*)d_ws;

  // ws: wsum fp32 @0 (262144 B); weff bf16 @262144 (98304 B); wtp bf16 @360448 (98304 B)
  float*          wsum = (float*)ws;
  unsigned short* weff = (unsigned short*)(ws + 262144);
  unsigned short* wtp  = (unsigned short*)(ws + 360448);

  k_wsum<<<256, 256, 0, stream>>>(w_head, wsum);
  k_pre2<<<448, 256, 0, stream>>>(w_body, wsum, weff, w_tail, wtp);
  // grid 896 divisible by 8: bijective XCD swizzle, cpx = 896/8 = 112
  k_all <<<896, 256, 0, stream>>>(x, weff, wtp, b_tail, out, 112u);
}

// Round 20
// 169.637 us; speedup vs baseline: 1.0308x; 1.0308x over previous
//
#include <hip/hip_runtime.h>
#include <stdint.h>

#define CIN 256
#define COUT 256
#define RANK 64
#define H_ 112
#define W_ 112
#define HW_ (112*112)

// y2 slab: 4 sub-slabs [114 w'][72 stride] bf16 at h-stride 8176 (not 8208):
// the 32-ushort overlap between adjacent sub-slabs is w'=113-halo ∩ w'=0-halo,
// both zero-only (R18-verified benign). Total 3*8176+8208 = 32736 ushorts =
// 65472 B <= 64 KB workgroup limit.
#define HSTRIDE 8176

typedef short bf16x8 __attribute__((ext_vector_type(8)));   // 8 bf16 = 4 VGPRs
typedef float f32x4 __attribute__((ext_vector_type(4)));

__device__ __forceinline__ unsigned short rne1(float a){
  unsigned ua = __builtin_bit_cast(unsigned, a);
  ua += 0x7FFFu + ((ua >> 16) & 1u);
  return (unsigned short)(ua >> 16);
}
// packed fp32x2 -> bf16x2 (lo = a, hi = b), single VALU op
__device__ __forceinline__ unsigned cvtpk(float a, float b){
  unsigned r;
  asm("v_cvt_pk_bf16_f32 %0, %1, %2" : "=v"(r) : "v"(a), "v"(b));
  return r;
}

// ---- K0a: w_sum[o][i] = sum_k w_head[k][o][i] ----
__global__ __launch_bounds__(256) void k_wsum(const float* __restrict__ wh,
                                              float* __restrict__ wsum){
  int o = blockIdx.x, i = threadIdx.x;
  float s = 0.f;
  for (int k = 0; k < RANK; ++k) s += wh[(k*COUT + o)*CIN + i];
  wsum[o*CIN + i] = s;
}

// ---- K0b: blocks [0,192): w_eff[dh][r][i] (bf16); blocks [192,448): wtp[o][dw][r] (bf16)
__global__ __launch_bounds__(256) void k_pre2(const float* __restrict__ wb,
                                              const float* __restrict__ wsum,
                                              unsigned short* __restrict__ weff,
                                              const float* __restrict__ wt,
                                              unsigned short* __restrict__ wtp){
  const int tid = threadIdx.x;
  if (blockIdx.x < 192){
    int bid = blockIdx.x;            // dh*64 + r
    int dh = bid >> 6, r = bid & 63;
    float s = 0.f;
    for (int o = 0; o < COUT; ++o)
      s += wb[(r*COUT + o)*3 + dh] * wsum[o*CIN + tid];
    weff[bid*CIN + tid] = rne1(s);
  } else {
    int o = blockIdx.x - 192;
    if (tid < 192){
      int dw = tid >> 6, r = tid & 63;
      wtp[o*192 + tid] = rne1(wt[(o*RANK + r)*3 + dw]);
    }
  }
}

// ---- K_all: 512 threads / 8 waves, 4 h-rows per block (halo amp 2.0x -> 1.5x).
// Waves 0-5 stage x row h0-1+wid (fp32->bf16 transpose, depth-2 counted-vmcnt
// pipeline, split barriers); waves 6-7 are compute-only (A-frag loads only).
// Wave (hloc=wid>>1, rhalf=wid&1): phase A = 1 h x 32 r x 112 w; then
// acc -> y2 slab (4 sub-slabs, stride HSTRIDE); phase C = 1 h x 128 o.
// Stage layout per step: [6 rows][4 g][112 slots][8 c] bf16, slot = w^(g&3)^((w>>2)&3).
__global__ __launch_bounds__(512,2) void k_all(const float* __restrict__ x,
                                               const unsigned short* __restrict__ weff,
                                               const unsigned short* __restrict__ wtp,
                                               const float* __restrict__ bias,
                                               float* __restrict__ out,
                                               unsigned cpx){
  __shared__ alignas(16) unsigned short lds[32736];  // 65472 B: stage 43008 / slab 65472
  const int tid  = threadIdx.x;
  const int wid  = tid >> 6, lane = tid & 63, g = lane >> 4, l15 = lane & 15;
  const unsigned orig = blockIdx.x;
  const unsigned wg   = (orig & 7u)*cpx + (orig >> 3);   // bijective XCD swizzle
  const int bb   = wg / 28, hb = wg % 28;
  const int h0   = hb*4;
  const int hloc = wid >> 1, rhalf = wid & 1;
  const bool stager = (wid < 6);

  // staging lane roles: q_st = w-quad, cpair = channel pair 0..15
  const int q_st = lane & 3, cpair = lane >> 2;
  const int g_st = cpair >> 2, cp3 = cpair & 3;
  const int grow = h0 - 1 + wid;                       // meaningful for wid<6
  const bool rok = stager && (grow >= 0) && (grow < H_);
  const float* xrow = x + ((size_t)bb*CIN + cpair*2)*HW_
                        + (size_t)((rok ? grow : 0))*W_;
  unsigned char* const stg = (unsigned char*)lds;
  const int cxor = (g_st ^ q_st) & 3;                  // write slot XOR
  const int lxor = (l15 ^ (g & 3) ^ ((l15 >> 2) & 3)); // read slot low bits

  // ---- phase A: 8 steps x 32 ch; depth-2 reg pipeline ----
  f32x4 acc[2][7];
  #pragma unroll
  for (int a = 0; a < 2; ++a)
    #pragma unroll
    for (int b = 0; b < 7; ++b) acc[a][b] = (f32x4){0.f,0.f,0.f,0.f};

  f32x4  xa[2][7], xb[2][7];      // x fp32 in-flight, 2 sets (staging waves)
  bf16x8 afp[2][3][2];            // weff A-frags, 2 sets

  auto ISSUE_A = [&](int t){
    const int s = t & 1;
    #pragma unroll
    for (int dh = 0; dh < 3; ++dh){
      const unsigned short* ab = weff + (size_t)(dh*64 + rhalf*32 + l15)*CIN + t*32 + g*8;
      afp[s][dh][0] = *(const bf16x8*)(ab);
      afp[s][dh][1] = *(const bf16x8*)(ab + 16*CIN);
    }
  };
  auto ISSUE_X = [&](int t){
    const int s = t & 1;
    const float* pa = xrow + (size_t)t*32*HW_;
    #pragma unroll
    for (int j = 0; j < 7; ++j){
      const int w0 = 16*j + q_st*4;
      if (rok){
        xa[s][j] = *(const f32x4*)(pa + w0);
        xb[s][j] = *(const f32x4*)(pa + HW_ + w0);
      } else {
        xa[s][j] = (f32x4){0.f,0.f,0.f,0.f};
        xb[s][j] = (f32x4){0.f,0.f,0.f,0.f};
      }
    }
  };
  auto WRITE = [&](int t){
    const int s = t & 1;
    unsigned char* base = stg + wid*7168 + g_st*1792 + cp3*4;
    #pragma unroll
    for (int j = 0; j < 7; ++j){
      const int w0 = 16*j + q_st*4;
      #pragma unroll
      for (int k = 0; k < 4; ++k){
        unsigned pk = cvtpk(xa[s][j][k], xb[s][j][k]);
        *(unsigned*)(base + (unsigned)(w0*16) + (unsigned)((k ^ cxor) << 4)) = pk;
      }
    }
  };
  auto MSTEP = [&](int t){
    const int s = t & 1;
    #pragma unroll
    for (int dh = 0; dh < 3; ++dh){
      const unsigned char* rowb = stg + (hloc + dh)*7168 + g*1792 + lxor*16;
      #pragma unroll
      for (int wt = 0; wt < 7; ++wt){
        bf16x8 bfv = *(const bf16x8*)(rowb + wt*256);
        acc[0][wt] = __builtin_amdgcn_mfma_f32_16x16x32_bf16(afp[s][dh][0], bfv, acc[0][wt], 0, 0, 0);
        acc[1][wt] = __builtin_amdgcn_mfma_f32_16x16x32_bf16(afp[s][dh][1], bfv, acc[1][wt], 0, 0, 0);
      }
    }
  };

  ISSUE_A(0);
  if (stager) ISSUE_X(0);
  ISSUE_A(1);
  if (stager) ISSUE_X(1);
  #pragma unroll
  for (int t = 0; t < 8; ++t){
    // retire pair t, leave pair t+1 in flight (per-wave-role counts)
    if (t < 7){
      if (stager) asm volatile("s_waitcnt vmcnt(20)" ::: "memory"); // pair = 6 A + 14 X
      else        asm volatile("s_waitcnt vmcnt(6)"  ::: "memory"); // pair = 6 A
    } else {
      asm volatile("s_waitcnt vmcnt(0)" ::: "memory");
    }
    if (stager) WRITE(t);
    asm volatile("s_waitcnt lgkmcnt(0)" ::: "memory");   // ds_writes visible...
    __builtin_amdgcn_s_barrier();                        // ...to all waves; vm survives
    if (stager && t < 6) ISSUE_X(t + 2);  // x early: ~2-step prefetch distance
    MSTEP(t);                             // consumes afp[t&1]
    if (t < 6) ISSUE_A(t + 2);            // A-frags late (reuse afp[t&1] after use)
    __builtin_amdgcn_s_barrier();         // reads done before next WRITE
  }

  // ---- phase B: acc -> y2 slab, 4 sub-slabs [114 w'][72] @ stride HSTRIDE ----
  unsigned short* y2b = lds;
  if (tid < 64){                     // zero halo columns w'=0,113 for all 4 h
    int hh = tid >> 4, wsel = (tid >> 3) & 1, rq = tid & 7;
    *(uint4*)(y2b + hh*HSTRIDE + (wsel ? 113 : 0)*72 + rq*8) = (uint4){0,0,0,0};
  }
  #pragma unroll
  for (int wt = 0; wt < 7; ++wt){
    #pragma unroll
    for (int rt = 0; rt < 2; ++rt){
      uint2 st;
      st.x = cvtpk(acc[rt][wt][0], acc[rt][wt][1]);
      st.y = cvtpk(acc[rt][wt][2], acc[rt][wt][3]);
      *(uint2*)(y2b + hloc*HSTRIDE + (wt*16 + l15 + 1)*72 + rhalf*32 + rt*16 + g*4) = st;
    }
  }
  __syncthreads();

  // ---- phase C: tail GEMM, 4 passes of 32 o per wave ----
  const int h = h0 + hloc;
  #pragma unroll
  for (int opass = 0; opass < 4; ++opass){
    const int obase = rhalf*128 + opass*32;
    f32x4 a2[2][7];
    #pragma unroll
    for (int a = 0; a < 2; ++a)
      #pragma unroll
      for (int b = 0; b < 7; ++b) a2[a][b] = (f32x4){0.f,0.f,0.f,0.f};

    #pragma unroll
    for (int s = 0; s < 6; ++s){       // k-step: dw = s>>1, r-half = s&1
      bf16x8 afc[2];
      const unsigned short* ab = wtp + (size_t)(obase + l15)*192 + s*32 + g*8;
      #pragma unroll
      for (int rt = 0; rt < 2; ++rt)
        afc[rt] = *(const bf16x8*)(ab + rt*16*192);
      const unsigned short* qb = y2b + hloc*HSTRIDE + (l15 + (s >> 1))*72 + (s & 1)*32 + g*8;
      #pragma unroll
      for (int wt = 0; wt < 7; ++wt){
        bf16x8 bvv = *(const bf16x8*)(qb + wt*16*72);
        #pragma unroll
        for (int rt = 0; rt < 2; ++rt)
          a2[rt][wt] = __builtin_amdgcn_mfma_f32_16x16x32_bf16(afc[rt], bvv, a2[rt][wt], 0, 0, 0);
      }
    }

    float* ob = out + ((size_t)(bb*COUT) + obase)*HW_ + h*W_;
    #pragma unroll
    for (int rt = 0; rt < 2; ++rt){
      #pragma unroll
      for (int ii = 0; ii < 4; ++ii){
        float bvv = bias[obase + rt*16 + g*4 + ii];
        #pragma unroll
        for (int wt = 0; wt < 7; ++wt)
          ob[(size_t)(rt*16 + g*4 + ii)*HW_ + wt*16 + l15] = a2[rt][wt][ii] + bvv;
      }
    }
  }
}

extern "C" void kernel_launch(void* const* d_in, const int* in_sizes, int n_in,
                              void* d_out, int out_size, void* d_ws, size_t ws_size,
                              hipStream_t stream) {
  const float* x      = (const float*)d_in[0];
  const float* w_head = (const float*)d_in[1];
  const float* w_body = (const float*)d_in[2];
  const float* w_tail = (const float*)d_in[3];
  const float* b_tail = (const float*)d_in[4];
  float* out = (float*)d_out;
  char* ws = (char*)d_ws;

  // ws: wsum fp32 @0 (262144 B); weff bf16 @262144 (98304 B); wtp bf16 @360448 (98304 B)
  float*          wsum = (float*)ws;
  unsigned short* weff = (unsigned short*)(ws + 262144);
  unsigned short* wtp  = (unsigned short*)(ws + 360448);

  k_wsum<<<256, 256, 0, stream>>>(w_head, wsum);
  k_pre2<<<448, 256, 0, stream>>>(w_body, wsum, weff, w_tail, wtp);
  // grid 448 = 16 b x 28 h-quads, divisible by 8: bijective XCD swizzle, cpx = 56
  k_all <<<448, 512, 0, stream>>>(x, weff, wtp, b_tail, out, 56u);
}

// Round 21
// 168.927 us; speedup vs baseline: 1.0351x; 1.0042x over previous
//
#include <hip/hip_runtime.h>
#include <stdint.h>

#define CIN 256
#define COUT 256
#define RANK 64
#define H_ 112
#define W_ 112
#define HW_ (112*112)

// y2 slab: 4 sub-slabs [114 w'][72 stride] bf16 at h-stride 8176 (not 8208):
// the 32-ushort overlap between adjacent sub-slabs is w'=113-halo ∩ w'=0-halo,
// both zero-only (R18-verified benign). Total 3*8176+8208 = 32736 ushorts =
// 65472 B <= 64 KB workgroup limit.
#define HSTRIDE 8176

typedef short bf16x8 __attribute__((ext_vector_type(8)));   // 8 bf16 = 4 VGPRs
typedef float f32x4 __attribute__((ext_vector_type(4)));

__device__ __forceinline__ unsigned short rne1(float a){
  unsigned ua = __builtin_bit_cast(unsigned, a);
  ua += 0x7FFFu + ((ua >> 16) & 1u);
  return (unsigned short)(ua >> 16);
}
// packed fp32x2 -> bf16x2 (lo = a, hi = b), single VALU op
__device__ __forceinline__ unsigned cvtpk(float a, float b){
  unsigned r;
  asm("v_cvt_pk_bf16_f32 %0, %1, %2" : "=v"(r) : "v"(a), "v"(b));
  return r;
}

// ---- K0a: w_sum[o][i] = sum_k w_head[k][o][i] ----
__global__ __launch_bounds__(256) void k_wsum(const float* __restrict__ wh,
                                              float* __restrict__ wsum){
  int o = blockIdx.x, i = threadIdx.x;
  float s = 0.f;
  for (int k = 0; k < RANK; ++k) s += wh[(k*COUT + o)*CIN + i];
  wsum[o*CIN + i] = s;
}

// ---- K0b: blocks [0,192): w_eff[dh][r][i] (bf16); blocks [192,448): wtp[o][dw][r] (bf16)
__global__ __launch_bounds__(256) void k_pre2(const float* __restrict__ wb,
                                              const float* __restrict__ wsum,
                                              unsigned short* __restrict__ weff,
                                              const float* __restrict__ wt,
                                              unsigned short* __restrict__ wtp){
  const int tid = threadIdx.x;
  if (blockIdx.x < 192){
    int bid = blockIdx.x;            // dh*64 + r
    int dh = bid >> 6, r = bid & 63;
    float s = 0.f;
    for (int o = 0; o < COUT; ++o)
      s += wb[(r*COUT + o)*3 + dh] * wsum[o*CIN + tid];
    weff[bid*CIN + tid] = rne1(s);
  } else {
    int o = blockIdx.x - 192;
    if (tid < 192){
      int dw = tid >> 6, r = tid & 63;
      wtp[o*192 + tid] = rne1(wt[(o*RANK + r)*3 + dw]);
    }
  }
}

// ---- K_all: 512 threads / 8 waves, 4 h-rows per block (halo amp 2.0x -> 1.5x).
// Waves 0-5 stage x row h0-1+wid (fp32->bf16 transpose, depth-2 counted-vmcnt
// pipeline, split barriers); waves 6-7 are compute-only (A-frag loads only).
// Wave (hloc=wid>>1, rhalf=wid&1): phase A = 1 h x 32 r x 112 w; then
// acc -> y2 slab (4 sub-slabs, stride HSTRIDE); phase C = 1 h x 128 o.
// Stage layout per step: [6 rows][4 g][112 slots][8 c] bf16, slot = w^(g&3)^((w>>2)&3).
//
// SESSION RECORD (why this config): fused single-kernel beats split pipelines
// (R13: -310MB HBM vs xt-precompute, 181->162); depth-2 counted-vmcnt + split
// barriers is neutral-vs-R13 but keeps prefetch alive across barriers; the
// kernel is latency*concurrency-bound at the unified-register ceiling
// (~190 regs/wave -> ~8-10 waves/CU): R13/R18 showed relaxing regs/LDS moves
// nothing, R16/R17 showed forcing regs down spills catastrophically. 4-h-row
// blocks cut halo amplification 2.0x->1.5x (R20: k_all 160->155 in-env).
__global__ __launch_bounds__(512,2) void k_all(const float* __restrict__ x,
                                               const unsigned short* __restrict__ weff,
                                               const unsigned short* __restrict__ wtp,
                                               const float* __restrict__ bias,
                                               float* __restrict__ out,
                                               unsigned cpx){
  __shared__ alignas(16) unsigned short lds[32736];  // 65472 B: stage 43008 / slab 65472
  const int tid  = threadIdx.x;
  const int wid  = tid >> 6, lane = tid & 63, g = lane >> 4, l15 = lane & 15;
  const unsigned orig = blockIdx.x;
  const unsigned wg   = (orig & 7u)*cpx + (orig >> 3);   // bijective XCD swizzle
  const int bb   = wg / 28, hb = wg % 28;
  const int h0   = hb*4;
  const int hloc = wid >> 1, rhalf = wid & 1;
  const bool stager = (wid < 6);

  // staging lane roles: q_st = w-quad, cpair = channel pair 0..15
  const int q_st = lane & 3, cpair = lane >> 2;
  const int g_st = cpair >> 2, cp3 = cpair & 3;
  const int grow = h0 - 1 + wid;                       // meaningful for wid<6
  const bool rok = stager && (grow >= 0) && (grow < H_);
  const float* xrow = x + ((size_t)bb*CIN + cpair*2)*HW_
                        + (size_t)((rok ? grow : 0))*W_;
  unsigned char* const stg = (unsigned char*)lds;
  const int cxor = (g_st ^ q_st) & 3;                  // write slot XOR
  const int lxor = (l15 ^ (g & 3) ^ ((l15 >> 2) & 3)); // read slot low bits

  // ---- phase A: 8 steps x 32 ch; depth-2 reg pipeline ----
  f32x4 acc[2][7];
  #pragma unroll
  for (int a = 0; a < 2; ++a)
    #pragma unroll
    for (int b = 0; b < 7; ++b) acc[a][b] = (f32x4){0.f,0.f,0.f,0.f};

  f32x4  xa[2][7], xb[2][7];      // x fp32 in-flight, 2 sets (staging waves)
  bf16x8 afp[2][3][2];            // weff A-frags, 2 sets

  auto ISSUE_A = [&](int t){
    const int s = t & 1;
    #pragma unroll
    for (int dh = 0; dh < 3; ++dh){
      const unsigned short* ab = weff + (size_t)(dh*64 + rhalf*32 + l15)*CIN + t*32 + g*8;
      afp[s][dh][0] = *(const bf16x8*)(ab);
      afp[s][dh][1] = *(const bf16x8*)(ab + 16*CIN);
    }
  };
  auto ISSUE_X = [&](int t){
    const int s = t & 1;
    const float* pa = xrow + (size_t)t*32*HW_;
    #pragma unroll
    for (int j = 0; j < 7; ++j){
      const int w0 = 16*j + q_st*4;
      if (rok){
        xa[s][j] = *(const f32x4*)(pa + w0);
        xb[s][j] = *(const f32x4*)(pa + HW_ + w0);
      } else {
        xa[s][j] = (f32x4){0.f,0.f,0.f,0.f};
        xb[s][j] = (f32x4){0.f,0.f,0.f,0.f};
      }
    }
  };
  auto WRITE = [&](int t){
    const int s = t & 1;
    unsigned char* base = stg + wid*7168 + g_st*1792 + cp3*4;
    #pragma unroll
    for (int j = 0; j < 7; ++j){
      const int w0 = 16*j + q_st*4;
      #pragma unroll
      for (int k = 0; k < 4; ++k){
        unsigned pk = cvtpk(xa[s][j][k], xb[s][j][k]);
        *(unsigned*)(base + (unsigned)(w0*16) + (unsigned)((k ^ cxor) << 4)) = pk;
      }
    }
  };
  auto MSTEP = [&](int t){
    const int s = t & 1;
    #pragma unroll
    for (int dh = 0; dh < 3; ++dh){
      const unsigned char* rowb = stg + (hloc + dh)*7168 + g*1792 + lxor*16;
      #pragma unroll
      for (int wt = 0; wt < 7; ++wt){
        bf16x8 bfv = *(const bf16x8*)(rowb + wt*256);
        acc[0][wt] = __builtin_amdgcn_mfma_f32_16x16x32_bf16(afp[s][dh][0], bfv, acc[0][wt], 0, 0, 0);
        acc[1][wt] = __builtin_amdgcn_mfma_f32_16x16x32_bf16(afp[s][dh][1], bfv, acc[1][wt], 0, 0, 0);
      }
    }
  };

  ISSUE_A(0);
  if (stager) ISSUE_X(0);
  ISSUE_A(1);
  if (stager) ISSUE_X(1);
  #pragma unroll
  for (int t = 0; t < 8; ++t){
    // retire pair t, leave pair t+1 in flight (per-wave-role counts)
    if (t < 7){
      if (stager) asm volatile("s_waitcnt vmcnt(20)" ::: "memory"); // pair = 6 A + 14 X
      else        asm volatile("s_waitcnt vmcnt(6)"  ::: "memory"); // pair = 6 A
    } else {
      asm volatile("s_waitcnt vmcnt(0)" ::: "memory");
    }
    if (stager) WRITE(t);
    asm volatile("s_waitcnt lgkmcnt(0)" ::: "memory");   // ds_writes visible...
    __builtin_amdgcn_s_barrier();                        // ...to all waves; vm survives
    if (stager && t < 6) ISSUE_X(t + 2);  // x early: ~2-step prefetch distance
    MSTEP(t);                             // consumes afp[t&1]
    if (t < 6) ISSUE_A(t + 2);            // A-frags late (reuse afp[t&1] after use)
    __builtin_amdgcn_s_barrier();         // reads done before next WRITE
  }

  // ---- phase B: acc -> y2 slab, 4 sub-slabs [114 w'][72] @ stride HSTRIDE ----
  unsigned short* y2b = lds;
  if (tid < 64){                     // zero halo columns w'=0,113 for all 4 h
    int hh = tid >> 4, wsel = (tid >> 3) & 1, rq = tid & 7;
    *(uint4*)(y2b + hh*HSTRIDE + (wsel ? 113 : 0)*72 + rq*8) = (uint4){0,0,0,0};
  }
  #pragma unroll
  for (int wt = 0; wt < 7; ++wt){
    #pragma unroll
    for (int rt = 0; rt < 2; ++rt){
      uint2 st;
      st.x = cvtpk(acc[rt][wt][0], acc[rt][wt][1]);
      st.y = cvtpk(acc[rt][wt][2], acc[rt][wt][3]);
      *(uint2*)(y2b + hloc*HSTRIDE + (wt*16 + l15 + 1)*72 + rhalf*32 + rt*16 + g*4) = st;
    }
  }
  __syncthreads();

  // ---- phase C: tail GEMM, 4 passes of 32 o per wave ----
  const int h = h0 + hloc;
  #pragma unroll
  for (int opass = 0; opass < 4; ++opass){
    const int obase = rhalf*128 + opass*32;
    f32x4 a2[2][7];
    #pragma unroll
    for (int a = 0; a < 2; ++a)
      #pragma unroll
      for (int b = 0; b < 7; ++b) a2[a][b] = (f32x4){0.f,0.f,0.f,0.f};

    #pragma unroll
    for (int s = 0; s < 6; ++s){       // k-step: dw = s>>1, r-half = s&1
      bf16x8 afc[2];
      const unsigned short* ab = wtp + (size_t)(obase + l15)*192 + s*32 + g*8;
      #pragma unroll
      for (int rt = 0; rt < 2; ++rt)
        afc[rt] = *(const bf16x8*)(ab + rt*16*192);
      const unsigned short* qb = y2b + hloc*HSTRIDE + (l15 + (s >> 1))*72 + (s & 1)*32 + g*8;
      #pragma unroll
      for (int wt = 0; wt < 7; ++wt){
        bf16x8 bvv = *(const bf16x8*)(qb + wt*16*72);
        #pragma unroll
        for (int rt = 0; rt < 2; ++rt)
          a2[rt][wt] = __builtin_amdgcn_mfma_f32_16x16x32_bf16(afc[rt], bvv, a2[rt][wt], 0, 0, 0);
      }
    }

    float* ob = out + ((size_t)(bb*COUT) + obase)*HW_ + h*W_;
    #pragma unroll
    for (int rt = 0; rt < 2; ++rt){
      #pragma unroll
      for (int ii = 0; ii < 4; ++ii){
        float bvv = bias[obase + rt*16 + g*4 + ii];
        #pragma unroll
        for (int wt = 0; wt < 7; ++wt)
          ob[(size_t)(rt*16 + g*4 + ii)*HW_ + wt*16 + l15] = a2[rt][wt][ii] + bvv;
      }
    }
  }
}

extern "C" void kernel_launch(void* const* d_in, const int* in_sizes, int n_in,
                              void* d_out, int out_size, void* d_ws, size_t ws_size,
                              hipStream_t stream) {
  const float* x      = (const float*)d_in[0];
  const float* w_head = (const float*)d_in[1];
  const float* w_body = (const float*)d_in[2];
  const float* w_tail = (const float*)d_in[3];
  const float* b_tail = (const float*)d_in[4];
  float* out = (float*)d_out;
  char* ws = (char*)d_ws;

  // ws: wsum fp32 @0 (262144 B); weff bf16 @262144 (98304 B); wtp bf16 @360448 (98304 B)
  float*          wsum = (float*)ws;
  unsigned short* weff = (unsigned short*)(ws + 262144);
  unsigned short* wtp  = (unsigned short*)(ws + 360448);

  k_wsum<<<256, 256, 0, stream>>>(w_head, wsum);
  k_pre2<<<448, 256, 0, stream>>>(w_body, wsum, weff, w_tail, wtp);
  // grid 448 = 16 b x 28 h-quads, divisible by 8: bijective XCD swizzle, cpx = 56
  k_all <<<448, 512, 0, stream>>>(x, weff, wtp, b_tail, out, 56u);
}